// Round 13
// baseline (208.739 us; speedup 1.0000x reference)
//
#include <hip/hip_runtime.h>
#include <hip/hip_bf16.h>

#define B_   16
#define CIN  256
#define COUT 256
#define HH   64
#define WW   64
#define WDIM 512
#define OH   128
#define OW   128

typedef __attribute__((ext_vector_type(8))) short short8;
typedef __attribute__((ext_vector_type(4))) float f32x4;

__device__ __forceinline__ unsigned short f2bf(float f) {
    __hip_bfloat16 h = __float2bfloat16(f);
    return *reinterpret_cast<unsigned short*>(&h);
}
__device__ __forceinline__ float bf2f(unsigned short u) {
    unsigned int t = ((unsigned int)u) << 16;
    return *reinterpret_cast<float*>(&t);
}

// ws layout: bytes [0..16640) float scratch (sumsq partials + styles)
//            byte 32768: wb bf16 [16][256 o][256 i]  (2 MB)

__global__ __launch_bounds__(256) void k_styles(const float* __restrict__ w,
                                                const float* __restrict__ aw,
                                                const float* __restrict__ ab,
                                                float* __restrict__ ws) {
    int b = blockIdx.x, i = threadIdx.x;
    const float4* wr = (const float4*)(w + b * WDIM);
    const float4* ar = (const float4*)(aw + (size_t)i * WDIM);
    float acc = 0.f;
    #pragma unroll 4
    for (int k = 0; k < WDIM / 4; ++k) {
        float4 wv = wr[k], av = ar[k];
        acc += wv.x * av.x + wv.y * av.y + wv.z * av.z + wv.w * av.w;
    }
    const float wg = 0.04419417382415922f; // 1/sqrt(512)
    float st = acc * wg + ab[i];
    ws[64 + b * CIN + i] = st;
    __shared__ float sred[256];
    sred[i] = st * st;
    __syncthreads();
    for (int s = 128; s > 0; s >>= 1) {
        if (i < s) sred[i] += sred[i + s];
        __syncthreads();
    }
    if (i == 0) ws[b] = sred[0];
}

__global__ __launch_bounds__(64) void k_wb(const float* __restrict__ weight,
                                           const float* __restrict__ ws,
                                           unsigned short* __restrict__ wb) {
    int o = blockIdx.x, b = blockIdx.y, l = threadIdx.x;
    float tot = 0.f;
    #pragma unroll
    for (int j = 0; j < B_; ++j) tot += ws[j];
    float srs = rsqrtf(tot / (float)(B_ * CIN));
    float4 wk = *(const float4*)(weight + (size_t)o * CIN + l * 4);
    float ss = wk.x * wk.x + wk.y * wk.y + wk.z * wk.z + wk.w * wk.w;
    #pragma unroll
    for (int off = 32; off; off >>= 1) ss += __shfl_xor(ss, off);
    float wkn = rsqrtf(ss / (float)CIN);
    float4 st = *(const float4*)(ws + 64 + b * CIN + l * 4);
    float4 t;
    t.x = wk.x * wkn * st.x * srs;
    t.y = wk.y * wkn * st.y * srs;
    t.z = wk.z * wkn * st.z * srs;
    t.w = wk.w * wkn * st.w * srs;
    float s2 = t.x * t.x + t.y * t.y + t.z * t.z + t.w * t.w;
    #pragma unroll
    for (int off = 32; off; off >>= 1) s2 += __shfl_xor(s2, off);
    float dcoef = rsqrtf(s2 + 1e-8f);
    ushort4 pk;
    pk.x = f2bf(t.x * dcoef);
    pk.y = f2bf(t.y * dcoef);
    pk.z = f2bf(t.z * dcoef);
    pk.w = f2bf(t.w * dcoef);
    *(ushort4*)(wb + ((size_t)b * COUT + o) * CIN + l * 4) = pk;
}

// Fused conv + bilinear-2x upsample, LDS-aliased (R11 structure, verified
// numerics; 64KB LDS -> 2 blocks/CU).
// Phase 1: stage x rows {r, min(r+1,63)} into swizzled xt (64KB).
// Phase 2: ALL MFMAs (both 16-o chunks per wave) into 64 acc VGPRs.
// Phase 3: (xt dead) overlay yl[256 o][64 u32] on the same LDS; write y bf16
//          pairs rotation-swizzled.
// Phase 4: R11's verified epilogue: out rows {2r+1, 2r+2} (+row 0 at r=0).
__global__ __launch_bounds__(512, 4) void k_fused3(const float* __restrict__ x,
                                                   const float* __restrict__ bias,
                                                   const unsigned short* __restrict__ wb,
                                                   float* __restrict__ out) {
    __shared__ __align__(16) unsigned char smem[65536];
    unsigned short* xt = (unsigned short*)smem;   // [128 px][256 ch] swizzled
    unsigned int*  yl = (unsigned int*)smem;      // [256 o][64 u32] rotated (aliased)

    const int r = blockIdx.x;
    const int b = blockIdx.y;
    const int tid = threadIdx.x;
    const int lane = tid & 63;
    const int wv = tid >> 6;
    const int lo = lane & 15, hi = lane >> 4;

    const unsigned short* wbb = wb + (size_t)b * COUT * CIN;
    const int m0_0 = wv * 32;
    const int m0_1 = wv * 32 + 16;

    // ---- prefetch chunk-0 wb B-frags (hidden under staging) ----
    short8 breg[8];
    {
        const unsigned short* wr0 = wbb + (size_t)(m0_0 + lo) * CIN + hi * 8;
        #pragma unroll
        for (int ks = 0; ks < 8; ++ks) breg[ks] = *(const short8*)(wr0 + ks * 32);
    }

    // ---- Phase 1: stage x rows {r, min(r+1,63)} -> swizzled bf16 [px][i] ----
    // xt u16 idx = px*256 + (swz<<3) + (i&7), ib=i>>3,
    // swz = ib ^ (px&31) ^ ((px>>2)&7)   [verbatim R11 / conv5, verified]
    {
        const int c4 = tid & 15;
        const int rowsel = (tid >> 4) & 1;
        const int ig = tid >> 5;
        const int grow = min(r + rowsel, HH - 1);
        const float* xp = x + (size_t)b * CIN * (HH * WW) + (size_t)grow * WW + c4 * 4;
        const int pxbase = rowsel * 64 + c4 * 4;
        #pragma unroll
        for (int p = 0; p < 8; ++p) {
            const int i0 = ig * 16 + p * 2;
            float4 v0 = *(const float4*)(xp + (size_t)i0 * (HH * WW));
            float4 v1 = *(const float4*)(xp + (size_t)(i0 + 1) * (HH * WW));
            const int ib = i0 >> 3, e = i0 & 7;
            #pragma unroll
            for (int j = 0; j < 4; ++j) {
                const int px = pxbase + j;
                float f0 = (j == 0) ? v0.x : (j == 1) ? v0.y : (j == 2) ? v0.z : v0.w;
                float f1 = (j == 0) ? v1.x : (j == 1) ? v1.y : (j == 2) ? v1.z : v1.w;
                unsigned int pk = (unsigned int)f2bf(f0) | ((unsigned int)f2bf(f1) << 16);
                const int swz = ib ^ (px & 31) ^ ((px >> 2) & 7);
                *(unsigned int*)&xt[px * 256 + (swz << 3) + e] = pk;
            }
        }
    }
    __syncthreads();

    // ---- Phase 2: all MFMAs (A = x from LDS, B = wb regs; conv5 order) ----
    // D: col(o) = lane&15 -> o = m0+lo; row(px) = hi*4+j -> px = g*16+hi*4+j
    f32x4 acc0[8], acc1[8];
    #pragma unroll
    for (int g = 0; g < 8; ++g) {
        f32x4 a4 = {0.f, 0.f, 0.f, 0.f};
        #pragma unroll
        for (int ks = 0; ks < 8; ++ks) {
            const int px = g * 16 + lo;
            const int ib = ks * 4 + hi;
            const int swz = ib ^ (px & 31) ^ ((px >> 2) & 7);
            short8 a = *(const short8*)&xt[px * 256 + (swz << 3)];
            a4 = __builtin_amdgcn_mfma_f32_16x16x32_bf16(a, breg[ks], a4, 0, 0, 0);
        }
        acc0[g] = a4;
    }
    {   // reload wb frags for chunk 1
        const unsigned short* wr1 = wbb + (size_t)(m0_1 + lo) * CIN + hi * 8;
        #pragma unroll
        for (int ks = 0; ks < 8; ++ks) breg[ks] = *(const short8*)(wr1 + ks * 32);
    }
    #pragma unroll
    for (int g = 0; g < 8; ++g) {
        f32x4 a4 = {0.f, 0.f, 0.f, 0.f};
        #pragma unroll
        for (int ks = 0; ks < 8; ++ks) {
            const int px = g * 16 + lo;
            const int ib = ks * 4 + hi;
            const int swz = ib ^ (px & 31) ^ ((px >> 2) & 7);
            short8 a = *(const short8*)&xt[px * 256 + (swz << 3)];
            a4 = __builtin_amdgcn_mfma_f32_16x16x32_bf16(a, breg[ks], a4, 0, 0, 0);
        }
        acc1[g] = a4;
    }
    __syncthreads();   // xt dead from here

    // ---- Phase 3: write y into rotation-swizzled yl (verbatim R11) ----
    // pair p2 = g*8 + hi*2 (px = 2*p2, 2*p2+1); yl[o][(p2 + 2*(o&15)) & 63]
    #pragma unroll
    for (int c = 0; c < 2; ++c) {
        const int m0 = c ? m0_1 : m0_0;
        const int o = m0 + lo;
        const float bs = bias[o];
        const int rot = 2 * (o & 15);
        unsigned int* yrow = &yl[o * 64];
        #pragma unroll
        for (int g = 0; g < 8; ++g) {
            f32x4 a4 = c ? acc1[g] : acc0[g];
            const int p2 = g * 8 + hi * 2;
            unsigned int u0 = (unsigned int)f2bf(a4[0] + bs) | ((unsigned int)f2bf(a4[1] + bs) << 16);
            unsigned int u1 = (unsigned int)f2bf(a4[2] + bs) | ((unsigned int)f2bf(a4[3] + bs) << 16);
            const int cc = (p2 + rot) & 63;   // even (p2, rot both even) -> cc+1 safe
            yrow[cc] = u0;
            yrow[cc + 1] = u1;
        }
    }
    __syncthreads();

    // ---- Phase 4: epilogue (verbatim R11, verified) ----
    const int ostart = (r == 0) ? 0 : (2 * r + 1);
    const int nrows = (r == 0) ? 3 : ((r == HH - 1) ? 1 : 2);
    const int iters = nrows * 16;
    const int h = tid >> 5;    // half-wave 0..15
    const int t = tid & 31;    // col-pair lane

    for (int i = 0; i < iters; ++i) {
        const int task = i * 16 + h;
        const int o = task & 255;
        const int ori = task >> 8;
        const int orow = ostart + ori;
        const int yr0 = (orow - 1) >> 1;
        const int lr0 = min(max(yr0, 0), HH - 1) - r;
        const int lr1 = min(yr0 + 1, HH - 1) - r;
        const float wr0 = (orow & 1) ? 0.75f : 0.25f;
        const float wr1 = 1.f - wr0;
        const int rot = 2 * (o & 15);
        const unsigned int* yrow = &yl[o * 64];
        unsigned int M0 = yrow[(lr0 * 32 + t + rot) & 63];
        unsigned int M1 = yrow[(lr1 * 32 + t + rot) & 63];
        float mB = bf2f((unsigned short)(M0 & 0xffff)), mC = bf2f((unsigned short)(M0 >> 16));
        float nB = bf2f((unsigned short)(M1 & 0xffff)), nC = bf2f((unsigned short)(M1 >> 16));
        float vB = wr0 * mB + wr1 * nB;
        float vC = wr0 * mC + wr1 * nC;
        float vA = __shfl_up(vC, 1, 32);   if (t == 0)  vA = vB;
        float vD = __shfl_down(vB, 1, 32); if (t == 31) vD = vC;
        float4 ov;
        ov.x = 0.25f * vA + 0.75f * vB;
        ov.y = 0.75f * vB + 0.25f * vC;
        ov.z = 0.25f * vB + 0.75f * vC;
        ov.w = 0.75f * vC + 0.25f * vD;
        float* op = out + (((size_t)(b * COUT + o) * OH) + orow) * OW + 4 * t;
        *(float4*)op = ov;
    }
}

extern "C" void kernel_launch(void* const* d_in, const int* in_sizes, int n_in,
                              void* d_out, int out_size, void* d_ws, size_t ws_size,
                              hipStream_t stream) {
    (void)in_sizes; (void)n_in; (void)out_size; (void)ws_size;
    const float* x      = (const float*)d_in[0];
    const float* w      = (const float*)d_in[1];
    const float* aw     = (const float*)d_in[2];
    const float* ab     = (const float*)d_in[3];
    const float* weight = (const float*)d_in[4];
    const float* bias   = (const float*)d_in[5];
    float* out = (float*)d_out;
    float* wsf = (float*)d_ws;
    unsigned short* wb = (unsigned short*)((char*)d_ws + 32768);

    hipLaunchKernelGGL(k_styles, dim3(16), dim3(256), 0, stream, w, aw, ab, wsf);
    hipLaunchKernelGGL(k_wb, dim3(COUT, B_), dim3(64), 0, stream, weight, wsf, wb);
    hipLaunchKernelGGL(k_fused3, dim3(HH, B_), dim3(512), 0, stream, x, bias, wb, out);
}

// Round 14
// 183.771 us; speedup vs baseline: 1.1359x; 1.1359x over previous
//
#include <hip/hip_runtime.h>
#include <hip/hip_bf16.h>

#define B_   16
#define CIN  256
#define COUT 256
#define HH   64
#define WW   64
#define WDIM 512
#define OH   128
#define OW   128

typedef __attribute__((ext_vector_type(8))) short short8;
typedef __attribute__((ext_vector_type(4))) float f32x4;

__device__ __forceinline__ unsigned short f2bf(float f) {
    __hip_bfloat16 h = __float2bfloat16(f);
    return *reinterpret_cast<unsigned short*>(&h);
}
__device__ __forceinline__ float bf2f(unsigned short u) {
    unsigned int t = ((unsigned int)u) << 16;
    return *reinterpret_cast<float*>(&t);
}

// ws layout: bytes [0..16640) float scratch (sumsq partials + styles)
//            byte 32768: wb bf16 [16][256 o][256 i]  (2 MB)

__global__ __launch_bounds__(256) void k_styles(const float* __restrict__ w,
                                                const float* __restrict__ aw,
                                                const float* __restrict__ ab,
                                                float* __restrict__ ws) {
    int b = blockIdx.x, i = threadIdx.x;
    const float4* wr = (const float4*)(w + b * WDIM);
    const float4* ar = (const float4*)(aw + (size_t)i * WDIM);
    float acc = 0.f;
    #pragma unroll 4
    for (int k = 0; k < WDIM / 4; ++k) {
        float4 wv = wr[k], av = ar[k];
        acc += wv.x * av.x + wv.y * av.y + wv.z * av.z + wv.w * av.w;
    }
    const float wg = 0.04419417382415922f; // 1/sqrt(512)
    float st = acc * wg + ab[i];
    ws[64 + b * CIN + i] = st;
    __shared__ float sred[256];
    sred[i] = st * st;
    __syncthreads();
    for (int s = 128; s > 0; s >>= 1) {
        if (i < s) sred[i] += sred[i + s];
        __syncthreads();
    }
    if (i == 0) ws[b] = sred[0];
}

__global__ __launch_bounds__(64) void k_wb(const float* __restrict__ weight,
                                           const float* __restrict__ ws,
                                           unsigned short* __restrict__ wb) {
    int o = blockIdx.x, b = blockIdx.y, l = threadIdx.x;
    float tot = 0.f;
    #pragma unroll
    for (int j = 0; j < B_; ++j) tot += ws[j];
    float srs = rsqrtf(tot / (float)(B_ * CIN));
    float4 wk = *(const float4*)(weight + (size_t)o * CIN + l * 4);
    float ss = wk.x * wk.x + wk.y * wk.y + wk.z * wk.z + wk.w * wk.w;
    #pragma unroll
    for (int off = 32; off; off >>= 1) ss += __shfl_xor(ss, off);
    float wkn = rsqrtf(ss / (float)CIN);
    float4 st = *(const float4*)(ws + 64 + b * CIN + l * 4);
    float4 t;
    t.x = wk.x * wkn * st.x * srs;
    t.y = wk.y * wkn * st.y * srs;
    t.z = wk.z * wkn * st.z * srs;
    t.w = wk.w * wkn * st.w * srs;
    float s2 = t.x * t.x + t.y * t.y + t.z * t.z + t.w * t.w;
    #pragma unroll
    for (int off = 32; off; off >>= 1) s2 += __shfl_xor(s2, off);
    float dcoef = rsqrtf(s2 + 1e-8f);
    ushort4 pk;
    pk.x = f2bf(t.x * dcoef);
    pk.y = f2bf(t.y * dcoef);
    pk.z = f2bf(t.z * dcoef);
    pk.w = f2bf(t.w * dcoef);
    *(ushort4*)(wb + ((size_t)b * COUT + o) * CIN + l * 4) = pk;
}

// Fused conv + bilinear-2x upsample, HALF-TILE LDS aliasing (no spill).
// xt lower 32KB = row r (px 0..63), upper 32KB = row r+1 (px 64..127).
// yl_r  (row r   y, [256 o][32 u32], per-half rotation) aliases lower 32KB.
// yl_r1 (row r+1 y)                                     aliases upper 32KB.
// Sequence: stage | MFMA lower | B | write yl_r + MFMA upper | B |
//           write yl_r1 | B | epilogue.  acc live <= 32 VGPR at a time.
__global__ __launch_bounds__(512, 4) void k_fused4(const float* __restrict__ x,
                                                   const float* __restrict__ bias,
                                                   const unsigned short* __restrict__ wb,
                                                   float* __restrict__ out) {
    __shared__ __align__(16) unsigned char smem[65536];
    unsigned short* xt  = (unsigned short*)smem;          // [128 px][256 ch] swizzled
    unsigned int*  ylr  = (unsigned int*)smem;            // [256 o][32 u32] row r
    unsigned int*  ylr1 = (unsigned int*)(smem + 32768);  // [256 o][32 u32] row r+1

    const int r = blockIdx.x;
    const int b = blockIdx.y;
    const int tid = threadIdx.x;
    const int lane = tid & 63;
    const int wv = tid >> 6;
    const int lo = lane & 15, hi = lane >> 4;

    const unsigned short* wbb = wb + (size_t)b * COUT * CIN;
    const int m0_0 = wv * 32;
    const int m0_1 = wv * 32 + 16;
    const unsigned short* wr0 = wbb + (size_t)(m0_0 + lo) * CIN + hi * 8;
    const unsigned short* wr1 = wbb + (size_t)(m0_1 + lo) * CIN + hi * 8;

    // ---- prefetch chunk-0 wb B-frags (hidden under staging) ----
    short8 breg[8];
    #pragma unroll
    for (int ks = 0; ks < 8; ++ks) breg[ks] = *(const short8*)(wr0 + ks * 32);

    // ---- Phase 1: stage x rows {r, min(r+1,63)} -> swizzled bf16 [px][i] ----
    // xt u16 idx = px*256 + (swz<<3) + (i&7), ib=i>>3,
    // swz = ib ^ (px&31) ^ ((px>>2)&7)   [verbatim R11, verified]
    {
        const int c4 = tid & 15;
        const int rowsel = (tid >> 4) & 1;
        const int ig = tid >> 5;
        const int grow = min(r + rowsel, HH - 1);
        const float* xp = x + (size_t)b * CIN * (HH * WW) + (size_t)grow * WW + c4 * 4;
        const int pxbase = rowsel * 64 + c4 * 4;
        #pragma unroll
        for (int p = 0; p < 8; ++p) {
            const int i0 = ig * 16 + p * 2;
            float4 v0 = *(const float4*)(xp + (size_t)i0 * (HH * WW));
            float4 v1 = *(const float4*)(xp + (size_t)(i0 + 1) * (HH * WW));
            const int ib = i0 >> 3, e = i0 & 7;
            #pragma unroll
            for (int j = 0; j < 4; ++j) {
                const int px = pxbase + j;
                float f0 = (j == 0) ? v0.x : (j == 1) ? v0.y : (j == 2) ? v0.z : v0.w;
                float f1 = (j == 0) ? v1.x : (j == 1) ? v1.y : (j == 2) ? v1.z : v1.w;
                unsigned int pk = (unsigned int)f2bf(f0) | ((unsigned int)f2bf(f1) << 16);
                const int swz = ib ^ (px & 31) ^ ((px >> 2) & 7);
                *(unsigned int*)&xt[px * 256 + (swz << 3) + e] = pk;
            }
        }
    }
    __syncthreads();

    // ---- Phase 2a: MFMA LOWER half (row r, g=0..3), both chunks ----
    f32x4 accL0[4], accL1[4];
    #pragma unroll
    for (int g = 0; g < 4; ++g) {
        f32x4 a4 = {0.f, 0.f, 0.f, 0.f};
        #pragma unroll
        for (int ks = 0; ks < 8; ++ks) {
            const int px = g * 16 + lo;
            const int ib = ks * 4 + hi;
            const int swz = ib ^ (px & 31) ^ ((px >> 2) & 7);
            short8 a = *(const short8*)&xt[px * 256 + (swz << 3)];
            a4 = __builtin_amdgcn_mfma_f32_16x16x32_bf16(a, breg[ks], a4, 0, 0, 0);
        }
        accL0[g] = a4;
    }
    #pragma unroll
    for (int ks = 0; ks < 8; ++ks) breg[ks] = *(const short8*)(wr1 + ks * 32);
    #pragma unroll
    for (int g = 0; g < 4; ++g) {
        f32x4 a4 = {0.f, 0.f, 0.f, 0.f};
        #pragma unroll
        for (int ks = 0; ks < 8; ++ks) {
            const int px = g * 16 + lo;
            const int ib = ks * 4 + hi;
            const int swz = ib ^ (px & 31) ^ ((px >> 2) & 7);
            short8 a = *(const short8*)&xt[px * 256 + (swz << 3)];
            a4 = __builtin_amdgcn_mfma_f32_16x16x32_bf16(a, breg[ks], a4, 0, 0, 0);
        }
        accL1[g] = a4;
    }
    __syncthreads();   // all lower-half xt reads done

    // ---- Phase 3a: write y row r into ylr (aliases xt lower 32KB) ----
    // D: col(o)=lo -> o=m0+lo; row(px)=hi*4+j -> pair p2 = g*8+hi*2 (0..30)
    // idx = o*32 + ((p2 + rot) & 31), rot = 2*(o&15) = 2*lo (even, in-half)
    #pragma unroll
    for (int c = 0; c < 2; ++c) {
        const int m0 = c ? m0_1 : m0_0;
        const int o = m0 + lo;
        const float bs = bias[o];
        const int rot = 2 * lo;
        unsigned int* yrow = &ylr[o * 32];
        #pragma unroll
        for (int g = 0; g < 4; ++g) {
            f32x4 a4 = c ? accL1[g] : accL0[g];
            const int p2 = g * 8 + hi * 2;
            unsigned int u0 = (unsigned int)f2bf(a4[0] + bs) | ((unsigned int)f2bf(a4[1] + bs) << 16);
            unsigned int u1 = (unsigned int)f2bf(a4[2] + bs) | ((unsigned int)f2bf(a4[3] + bs) << 16);
            const int cc = (p2 + rot) & 31;   // even -> cc+1 <= 31
            yrow[cc] = u0;
            yrow[cc + 1] = u1;
        }
    }

    // ---- Phase 2b: MFMA UPPER half (row r+1, g=4..7), both chunks ----
    f32x4 accH0[4], accH1[4];
    #pragma unroll
    for (int ks = 0; ks < 8; ++ks) breg[ks] = *(const short8*)(wr0 + ks * 32);
    #pragma unroll
    for (int g = 0; g < 4; ++g) {
        f32x4 a4 = {0.f, 0.f, 0.f, 0.f};
        #pragma unroll
        for (int ks = 0; ks < 8; ++ks) {
            const int px = (g + 4) * 16 + lo;
            const int ib = ks * 4 + hi;
            const int swz = ib ^ (px & 31) ^ ((px >> 2) & 7);
            short8 a = *(const short8*)&xt[px * 256 + (swz << 3)];
            a4 = __builtin_amdgcn_mfma_f32_16x16x32_bf16(a, breg[ks], a4, 0, 0, 0);
        }
        accH0[g] = a4;
    }
    #pragma unroll
    for (int ks = 0; ks < 8; ++ks) breg[ks] = *(const short8*)(wr1 + ks * 32);
    #pragma unroll
    for (int g = 0; g < 4; ++g) {
        f32x4 a4 = {0.f, 0.f, 0.f, 0.f};
        #pragma unroll
        for (int ks = 0; ks < 8; ++ks) {
            const int px = (g + 4) * 16 + lo;
            const int ib = ks * 4 + hi;
            const int swz = ib ^ (px & 31) ^ ((px >> 2) & 7);
            short8 a = *(const short8*)&xt[px * 256 + (swz << 3)];
            a4 = __builtin_amdgcn_mfma_f32_16x16x32_bf16(a, breg[ks], a4, 0, 0, 0);
        }
        accH1[g] = a4;
    }
    __syncthreads();   // all upper-half xt reads done

    // ---- Phase 3b: write y row r+1 into ylr1 (aliases xt upper 32KB) ----
    #pragma unroll
    for (int c = 0; c < 2; ++c) {
        const int m0 = c ? m0_1 : m0_0;
        const int o = m0 + lo;
        const float bs = bias[o];
        const int rot = 2 * lo;
        unsigned int* yrow = &ylr1[o * 32];
        #pragma unroll
        for (int g = 0; g < 4; ++g) {
            f32x4 a4 = c ? accH1[g] : accH0[g];
            const int tp = g * 8 + hi * 2;       // local pair in row r+1
            unsigned int u0 = (unsigned int)f2bf(a4[0] + bs) | ((unsigned int)f2bf(a4[1] + bs) << 16);
            unsigned int u1 = (unsigned int)f2bf(a4[2] + bs) | ((unsigned int)f2bf(a4[3] + bs) << 16);
            const int cc = (tp + rot) & 31;
            yrow[cc] = u0;
            yrow[cc + 1] = u1;
        }
    }
    __syncthreads();

    // ---- Phase 4: epilogue (R11 interp, split-base reads) ----
    const int ostart = (r == 0) ? 0 : (2 * r + 1);
    const int nrows = (r == 0) ? 3 : ((r == HH - 1) ? 1 : 2);
    const int iters = nrows * 16;
    const int h = tid >> 5;    // half-wave 0..15
    const int t = tid & 31;    // pair lane

    const unsigned int* ybase = (const unsigned int*)smem;
    for (int i = 0; i < iters; ++i) {
        const int task = i * 16 + h;
        const int o = task & 255;
        const int ori = task >> 8;
        const int orow = ostart + ori;
        const int yr0 = (orow - 1) >> 1;
        const int lr0 = min(max(yr0, 0), HH - 1) - r;    // 0 or 1
        const int lr1 = min(yr0 + 1, HH - 1) - r;        // 0 or 1
        const float wr0 = (orow & 1) ? 0.75f : 0.25f;
        const float wr1 = 1.f - wr0;
        const int rot = 2 * (o & 15);
        const int ci = (t + rot) & 31;
        unsigned int M0 = ybase[lr0 * 8192 + o * 32 + ci];
        unsigned int M1 = ybase[lr1 * 8192 + o * 32 + ci];
        float mB = bf2f((unsigned short)(M0 & 0xffff)), mC = bf2f((unsigned short)(M0 >> 16));
        float nB = bf2f((unsigned short)(M1 & 0xffff)), nC = bf2f((unsigned short)(M1 >> 16));
        float vB = wr0 * mB + wr1 * nB;
        float vC = wr0 * mC + wr1 * nC;
        float vA = __shfl_up(vC, 1, 32);   if (t == 0)  vA = vB;
        float vD = __shfl_down(vB, 1, 32); if (t == 31) vD = vC;
        float4 ov;
        ov.x = 0.25f * vA + 0.75f * vB;
        ov.y = 0.75f * vB + 0.25f * vC;
        ov.z = 0.25f * vB + 0.75f * vC;
        ov.w = 0.75f * vC + 0.25f * vD;
        float* op = out + (((size_t)(b * COUT + o) * OH) + orow) * OW + 4 * t;
        *(float4*)op = ov;
    }
}

extern "C" void kernel_launch(void* const* d_in, const int* in_sizes, int n_in,
                              void* d_out, int out_size, void* d_ws, size_t ws_size,
                              hipStream_t stream) {
    (void)in_sizes; (void)n_in; (void)out_size; (void)ws_size;
    const float* x      = (const float*)d_in[0];
    const float* w      = (const float*)d_in[1];
    const float* aw     = (const float*)d_in[2];
    const float* ab     = (const float*)d_in[3];
    const float* weight = (const float*)d_in[4];
    const float* bias   = (const float*)d_in[5];
    float* out = (float*)d_out;
    float* wsf = (float*)d_ws;
    unsigned short* wb = (unsigned short*)((char*)d_ws + 32768);

    hipLaunchKernelGGL(k_styles, dim3(16), dim3(256), 0, stream, w, aw, ab, wsf);
    hipLaunchKernelGGL(k_wb, dim3(COUT, B_), dim3(64), 0, stream, weight, wsf, wb);
    hipLaunchKernelGGL(k_fused4, dim3(HH, B_), dim3(512), 0, stream, x, bias, wb, out);
}

// Round 15
// 110.432 us; speedup vs baseline: 1.8902x; 1.6641x over previous
//
#include <hip/hip_runtime.h>
#include <hip/hip_bf16.h>

#define B_   16
#define CIN  256
#define COUT 256
#define HH   64
#define WW   64
#define WDIM 512
#define OH   128
#define OW   128

typedef __attribute__((ext_vector_type(8))) short short8;
typedef __attribute__((ext_vector_type(4))) float f32x4;

__device__ __forceinline__ unsigned short f2bf(float f) {
    __hip_bfloat16 h = __float2bfloat16(f);
    return *reinterpret_cast<unsigned short*>(&h);
}
__device__ __forceinline__ float bf2f(unsigned short u) {
    unsigned int t = ((unsigned int)u) << 16;
    return *reinterpret_cast<float*>(&t);
}

// ws layout: bytes [0..16640) float scratch (sumsq partials + styles)
//            byte 32768:  wb bf16 [16][256 o][256 i]        (2 MB)
//            byte 4 MiB:  y  bf16 [16][256 o][64][64]       (33.5 MB)

__global__ __launch_bounds__(256) void k_styles(const float* __restrict__ w,
                                                const float* __restrict__ aw,
                                                const float* __restrict__ ab,
                                                float* __restrict__ ws) {
    int b = blockIdx.x, i = threadIdx.x;
    const float4* wr = (const float4*)(w + b * WDIM);
    const float4* ar = (const float4*)(aw + (size_t)i * WDIM);
    float acc = 0.f;
    #pragma unroll 4
    for (int k = 0; k < WDIM / 4; ++k) {
        float4 wv = wr[k], av = ar[k];
        acc += wv.x * av.x + wv.y * av.y + wv.z * av.z + wv.w * av.w;
    }
    const float wg = 0.04419417382415922f; // 1/sqrt(512)
    float st = acc * wg + ab[i];
    ws[64 + b * CIN + i] = st;
    __shared__ float sred[256];
    sred[i] = st * st;
    __syncthreads();
    for (int s = 128; s > 0; s >>= 1) {
        if (i < s) sred[i] += sred[i + s];
        __syncthreads();
    }
    if (i == 0) ws[b] = sred[0];
}

__global__ __launch_bounds__(64) void k_wb(const float* __restrict__ weight,
                                           const float* __restrict__ ws,
                                           unsigned short* __restrict__ wb) {
    int o = blockIdx.x, b = blockIdx.y, l = threadIdx.x;
    float tot = 0.f;
    #pragma unroll
    for (int j = 0; j < B_; ++j) tot += ws[j];
    float srs = rsqrtf(tot / (float)(B_ * CIN));
    float4 wk = *(const float4*)(weight + (size_t)o * CIN + l * 4);
    float ss = wk.x * wk.x + wk.y * wk.y + wk.z * wk.z + wk.w * wk.w;
    #pragma unroll
    for (int off = 32; off; off >>= 1) ss += __shfl_xor(ss, off);
    float wkn = rsqrtf(ss / (float)CIN);
    float4 st = *(const float4*)(ws + 64 + b * CIN + l * 4);
    float4 t;
    t.x = wk.x * wkn * st.x * srs;
    t.y = wk.y * wkn * st.y * srs;
    t.z = wk.z * wkn * st.z * srs;
    t.w = wk.w * wkn * st.w * srs;
    float s2 = t.x * t.x + t.y * t.y + t.z * t.z + t.w * t.w;
    #pragma unroll
    for (int off = 32; off; off >>= 1) s2 += __shfl_xor(s2, off);
    float dcoef = rsqrtf(s2 + 1e-8f);
    ushort4 pk;
    pk.x = f2bf(t.x * dcoef);
    pk.y = f2bf(t.y * dcoef);
    pk.z = f2bf(t.z * dcoef);
    pk.w = f2bf(t.w * dcoef);
    *(ushort4*)(wb + ((size_t)b * COUT + o) * CIN + l * 4) = pk;
}

// Conv5 — verbatim R8 (verified, best split). Block = 2 rows x 64 cols, 512 thr,
// waves split o (wb loaded once per wave), 1 barrier, direct ushort4 y stores.
__global__ __launch_bounds__(512, 4) void k_conv5(const float* __restrict__ x,
                                                  const float* __restrict__ bias,
                                                  const unsigned short* __restrict__ wb,
                                                  unsigned short* __restrict__ y) {
    __shared__ __align__(16) unsigned short xt[128 * CIN]; // 65536 B
    const int r2 = blockIdx.x * 2;
    const int b = blockIdx.y;
    const int tid = threadIdx.x;
    const int lane = tid & 63;
    const int wv = tid >> 6;
    const int lo = lane & 15, hi = lane >> 4;

    const unsigned short* wbb = wb + (size_t)b * COUT * CIN;
    short8 breg[2][8];
    #pragma unroll
    for (int c = 0; c < 2; ++c) {
        const int m0 = (wv * 2 + c) * 16;
        const unsigned short* wrow = wbb + (size_t)(m0 + lo) * CIN + hi * 8;
        #pragma unroll
        for (int ks = 0; ks < 8; ++ks)
            breg[c][ks] = *(const short8*)(wrow + ks * 32);
    }

    {
        const int c4 = tid & 15;
        const int rowsel = (tid >> 4) & 1;
        const int ig = tid >> 5;
        const float* xp = x + (size_t)b * CIN * (HH * WW) + (size_t)(r2 + rowsel) * WW + c4 * 4;
        const int pxbase = rowsel * 64 + c4 * 4;
        #pragma unroll
        for (int p = 0; p < 8; ++p) {
            const int i0 = ig * 16 + p * 2;
            float4 v0 = *(const float4*)(xp + (size_t)i0 * (HH * WW));
            float4 v1 = *(const float4*)(xp + (size_t)(i0 + 1) * (HH * WW));
            const int ib = i0 >> 3, e = i0 & 7;
            #pragma unroll
            for (int j = 0; j < 4; ++j) {
                const int px = pxbase + j;
                float f0 = (j == 0) ? v0.x : (j == 1) ? v0.y : (j == 2) ? v0.z : v0.w;
                float f1 = (j == 0) ? v1.x : (j == 1) ? v1.y : (j == 2) ? v1.z : v1.w;
                unsigned int pk = (unsigned int)f2bf(f0) | ((unsigned int)f2bf(f1) << 16);
                const int swz = ib ^ (px & 31) ^ ((px >> 2) & 7);
                *(unsigned int*)&xt[px * 256 + (swz << 3) + e] = pk;
            }
        }
    }
    __syncthreads();

    unsigned short* yb = y + (size_t)b * COUT * (HH * WW);

    #pragma unroll
    for (int c = 0; c < 2; ++c) {
        const int m0 = (wv * 2 + c) * 16;
        const float bs = bias[m0 + lo];
        unsigned short* yrow = yb + (size_t)(m0 + lo) * (HH * WW);
        #pragma unroll
        for (int g = 0; g < 8; ++g) {
            f32x4 acc = {0.f, 0.f, 0.f, 0.f};
            #pragma unroll
            for (int ks = 0; ks < 8; ++ks) {
                const int px = g * 16 + lo;
                const int ib = ks * 4 + hi;
                const int swz = ib ^ (px & 31) ^ ((px >> 2) & 7);
                short8 a = *(const short8*)&xt[px * 256 + (swz << 3)];
                acc = __builtin_amdgcn_mfma_f32_16x16x32_bf16(a, breg[c][ks], acc, 0, 0, 0);
            }
            ushort4 pk;
            pk.x = f2bf(acc[0] + bs);
            pk.y = f2bf(acc[1] + bs);
            pk.z = f2bf(acc[2] + bs);
            pk.w = f2bf(acc[3] + bs);
            const int prow = g >> 2;
            const int pcol = (g & 3) * 16 + hi * 4;
            *(ushort4*)(yrow + (size_t)(r2 + prow) * WW + pcol) = pk;
        }
    }
}

// k_up2: one block per (b,ch). Stage the full 8KB y channel image into LDS
// once (coalesced uint4, 1x read amplification), then each half-wave emits
// full 512B output rows. Row/col interp formulas identical to R8's verified
// k_up (re-derived: even oc=2m -> 0.25 y[m-1] + 0.75 y[m]; odd -> 0.75/0.25).
#define YP 72   // padded u16 stride (144B rows: 16B-aligned, bank-rotating)
__global__ __launch_bounds__(256, 4) void k_up2(const unsigned short* __restrict__ y,
                                                float* __restrict__ out) {
    __shared__ __align__(16) unsigned short ylds[HH * YP]; // 9216 B
    const int id = blockIdx.x;          // b*COUT + ch
    const int tid = threadIdx.x;

    // ---- stage 8KB: 2 x uint4 per thread, coalesced ----
    {
        const uint4* src = (const uint4*)(y + (size_t)id * (HH * WW));
        uint4 v0 = src[tid * 2];
        uint4 v1 = src[tid * 2 + 1];
        const int row = tid >> 2;          // 0..63
        const int cu = (tid & 3) * 16;     // u16 col within row
        *(uint4*)&ylds[row * YP + cu] = v0;
        *(uint4*)&ylds[row * YP + cu + 8] = v1;
    }
    __syncthreads();

    const int t = tid & 31;     // output col quad: cols 4t..4t+3
    const int oru = tid >> 5;   // row group 0..7
    const int c0 = max(2 * t - 1, 0);
    const int c1 = 2 * t;
    const int c2 = 2 * t + 1;
    const int c3 = min(2 * t + 2, WW - 1);
    float* ob = out + (size_t)id * (OH * OW);

    #pragma unroll
    for (int i = 0; i < 16; ++i) {
        const int orow = oru * 16 + i;          // 0..127
        const int raw = (orow - 1) >> 1;        // -1..63
        const int yr0 = max(raw, 0);
        const int yr1 = min(raw + 1, HH - 1);
        const float wr0 = (orow & 1) ? 0.75f : 0.25f;
        const float wr1 = 1.f - wr0;
        const unsigned short* R0 = &ylds[yr0 * YP];
        const unsigned short* R1 = &ylds[yr1 * YP];
        float vA = wr0 * bf2f(R0[c0]) + wr1 * bf2f(R1[c0]);
        float vB = wr0 * bf2f(R0[c1]) + wr1 * bf2f(R1[c1]);
        float vC = wr0 * bf2f(R0[c2]) + wr1 * bf2f(R1[c2]);
        float vD = wr0 * bf2f(R0[c3]) + wr1 * bf2f(R1[c3]);
        float4 ov;
        ov.x = 0.25f * vA + 0.75f * vB;
        ov.y = 0.75f * vB + 0.25f * vC;
        ov.z = 0.25f * vB + 0.75f * vC;
        ov.w = 0.75f * vC + 0.25f * vD;
        *(float4*)(ob + (size_t)orow * OW + 4 * t) = ov;
    }
}

extern "C" void kernel_launch(void* const* d_in, const int* in_sizes, int n_in,
                              void* d_out, int out_size, void* d_ws, size_t ws_size,
                              hipStream_t stream) {
    (void)in_sizes; (void)n_in; (void)out_size; (void)ws_size;
    const float* x      = (const float*)d_in[0];
    const float* w      = (const float*)d_in[1];
    const float* aw     = (const float*)d_in[2];
    const float* ab     = (const float*)d_in[3];
    const float* weight = (const float*)d_in[4];
    const float* bias   = (const float*)d_in[5];
    float* out = (float*)d_out;
    float* wsf = (float*)d_ws;
    unsigned short* wb = (unsigned short*)((char*)d_ws + 32768);
    unsigned short* y  = (unsigned short*)((char*)d_ws + (4u << 20));

    hipLaunchKernelGGL(k_styles, dim3(16), dim3(256), 0, stream, w, aw, ab, wsf);
    hipLaunchKernelGGL(k_wb, dim3(COUT, B_), dim3(64), 0, stream, weight, wsf, wb);
    hipLaunchKernelGGL(k_conv5, dim3(HH / 2, B_), dim3(512), 0, stream, x, bias, wb, y);
    hipLaunchKernelGGL(k_up2, dim3(B_ * COUT), dim3(256), 0, stream, y, out);
}